// Round 1
// baseline (8796.416 us; speedup 1.0000x reference)
//
#include <hip/hip_runtime.h>

#define BATCH  4096
#define HID    1024
#define NOUT   64
#define TSTEPS 25
#define KA     1088   // 64 (y_prev) + 1024 (h1)
#define KB     2048   // 1024 (h1) + 1024 (h2)
#define LDY    1600   // TSTEPS * NOUT

typedef __attribute__((ext_vector_type(8))) __bf16 bf16x8;
typedef __attribute__((ext_vector_type(4))) float  floatx4;

__device__ __forceinline__ unsigned short f2bf(float f) {
    union { float f; unsigned u; } v; v.f = f;
    unsigned r = v.u + 0x7fffu + ((v.u >> 16) & 1u);
    return (unsigned short)(r >> 16);
}
__device__ __forceinline__ float sigmf(float x) { return 1.0f / (1.0f + __expf(-x)); }
__device__ __forceinline__ float tanh_fast(float x) {
    float ax = fabsf(x);
    float e  = __expf(-2.0f * ax);
    float t  = (1.0f - e) / (1.0f + e);
    return copysignf(t, x);
}

#define GLDS16(gp, lp) __builtin_amdgcn_global_load_lds( \
    (const __attribute__((address_space(1))) void*)(gp), \
    (__attribute__((address_space(3))) void*)(lp), 16, 0, 0)

// Fused GEMM + LSTM cell.
// Computes G = X[4096,K] @ W[4096,K]^T  (W rows gate-major: gate*HID + j),
// then per (b, j): gates = G + ginit[b*gstride + gate*HID + j],
// c' = sig(f)*c + sig(i)*tanh(g); h = sig(o)*tanh(c'); h -> d1/d2 (bf16), dfp (fp32).
// Tile 128x128, 4 waves 2x2, mfma 16x16x32 bf16, BK=32, global_load_lds staging.
// N-mapping is gate-minor: n_local = 4*jj + gate, so a 64-wide wave tile owns
// 16 hidden units with all 4 gates (self-contained epilogue).
__global__ __launch_bounds__(256, 2) void lstm_gate_gemm(
    const unsigned short* __restrict__ X, int K,
    const unsigned short* __restrict__ W,
    const float* __restrict__ ginit, int gstride,
    float* __restrict__ cell,
    unsigned short* __restrict__ d1, int ld1, int off1,
    unsigned short* __restrict__ d2, int ld2, int off2,
    float* __restrict__ dfp)
{
    __shared__ __align__(16) char smem[16384];   // staging A(8K)+B(8K); reused as epilogue scratch

    const int tid  = threadIdx.x;
    const int lane = tid & 63;
    const int w    = tid >> 6;
    const int q    = lane >> 4;
    const int lr   = lane & 15;
    const int wm   = w >> 1;
    const int wn   = w & 1;
    const int m0   = blockIdx.x * 128;
    const int j0   = blockIdx.y * 32;

    // staging: slot s (16B) holds tile-row s>>2, k-group (s&3)^((row>>1)&3) (xor swizzle)
    const unsigned short* srcA[2];
    const unsigned short* srcB[2];
    char* ldsA[2];
    char* ldsB[2];
#pragma unroll
    for (int e = 0; e < 2; ++e) {
        int s   = e * 256 + tid;
        int row = s >> 2;
        int kg  = (s & 3) ^ ((row >> 1) & 3);
        srcA[e] = X + (size_t)(m0 + row) * K + kg * 8;
        int jj = row >> 2, gate = row & 3;
        srcB[e] = W + (size_t)(gate * HID + j0 + jj) * K + kg * 8;
        ldsA[e] = smem + (e * 256 + w * 64) * 16;
        ldsB[e] = smem + 8192 + (e * 256 + w * 64) * 16;
    }

    // fragment LDS offsets (same swizzle)
    unsigned offA[4], offB[4];
#pragma unroll
    for (int i = 0; i < 4; ++i) {
        int ra = wm * 64 + i * 16 + lr;
        offA[i] = (unsigned)((ra * 4 + (q ^ ((ra >> 1) & 3))) * 16);
        int rb = wn * 64 + i * 16 + lr;
        offB[i] = (unsigned)(8192 + (rb * 4 + (q ^ ((rb >> 1) & 3))) * 16);
    }

    floatx4 acc[4][4];
#pragma unroll
    for (int i = 0; i < 4; ++i)
#pragma unroll
        for (int j = 0; j < 4; ++j)
            acc[i][j] = floatx4{0.f, 0.f, 0.f, 0.f};

    const int kiters = K >> 5;
    for (int kt = 0; kt < kiters; ++kt) {
        const int koff = kt * 32;
#pragma unroll
        for (int e = 0; e < 2; ++e) {
            GLDS16(srcA[e] + koff, ldsA[e]);
            GLDS16(srcB[e] + koff, ldsB[e]);
        }
        __syncthreads();
        bf16x8 av[4], bv[4];
#pragma unroll
        for (int i = 0; i < 4; ++i) av[i] = *(const bf16x8*)(smem + offA[i]);
#pragma unroll
        for (int j = 0; j < 4; ++j) bv[j] = *(const bf16x8*)(smem + offB[j]);
#pragma unroll
        for (int i = 0; i < 4; ++i)
#pragma unroll
            for (int j = 0; j < 4; ++j)
                acc[i][j] = __builtin_amdgcn_mfma_f32_16x16x32_bf16(av[i], bv[j], acc[i][j], 0, 0, 0);
        __syncthreads();
    }

    // ---- epilogue: per-wave LDS transpose of 16x64 sub-tiles, then cell update
    const int jg = j0 + wn * 16 + lr;            // hidden index for read phase
    float* scratch = (float*)(void*)smem + w * (16 * 64);

#pragma unroll
    for (int i = 0; i < 4; ++i) {
        __syncthreads();
#pragma unroll
        for (int j = 0; j < 4; ++j)
#pragma unroll
            for (int r = 0; r < 4; ++r)
                scratch[(q * 4 + r) * 64 + j * 16 + lr] = acc[i][j][r];  // C/D: row=q*4+r, col=lr
        __syncthreads();
#pragma unroll
        for (int p = 0; p < 4; ++p) {
            int row = q + p * 4;
            const float4 g = *(const float4*)(scratch + row * 64 + lr * 4);  // (i,f,g,o)
            int b = m0 + wm * 64 + i * 16 + row;
            const float* gb = ginit + (size_t)b * gstride;
            float iv = sigmf(g.x + gb[jg]);
            float fv = sigmf(g.y + gb[HID + jg]);
            float gv = tanh_fast(g.z + gb[2 * HID + jg]);
            float ov = sigmf(g.w + gb[3 * HID + jg]);
            size_t ci = (size_t)b * HID + jg;
            float cn = fv * cell[ci] + iv * gv;
            cell[ci] = cn;
            float hv = ov * tanh_fast(cn);
            unsigned short hb = f2bf(hv);
            d1[(size_t)b * ld1 + off1 + jg] = hb;
            if (d2)  d2[(size_t)b * ld2 + off2 + jg] = hb;
            if (dfp) dfp[(size_t)b * HID + jg] = hv;
        }
    }
}

// y = h2_f32 @ Wout^T + bout (fp32); writes d_out[:,t,:] and bf16 copy into next X0 (cols 0..63)
__global__ __launch_bounds__(256) void out_gemm(
    const float* __restrict__ h2, const float* __restrict__ wout,
    const float* __restrict__ bout, float* __restrict__ y,
    unsigned short* __restrict__ xn)
{
    int tid = blockIdx.x * 256 + threadIdx.x;
    int o = tid & 63, b = tid >> 6;
    const float* hr = h2 + (size_t)b * 1024;
    const float* wr = wout + (size_t)o * 1024;
    float acc = 0.f;
#pragma unroll 8
    for (int k = 0; k < 1024; k += 4) {
        float4 hv = *(const float4*)(hr + k);
        float4 wv = *(const float4*)(wr + k);
        acc += hv.x * wv.x + hv.y * wv.y + hv.z * wv.z + hv.w * wv.w;
    }
    float yv = acc + bout[o];
    y[(size_t)b * LDY + o] = yv;
    xn[(size_t)b * KA + o] = f2bf(yv);
}

// S0[b][n] = b_ih0[n] + b_hh0[n] + static[b,:] . W_ih0[n, 0:128]  (fp32, once)
__global__ __launch_bounds__(256) void s0_gemm(
    const float* __restrict__ stat, const float* __restrict__ wih,
    const float* __restrict__ bih, const float* __restrict__ bhh,
    float* __restrict__ s0)
{
    int idx = blockIdx.x * 256 + threadIdx.x;
    int n = idx & 4095;
    int b = idx >> 12;
    const float* xr = stat + (size_t)b * 128;
    const float* wr = wih + (size_t)n * 192;
    float acc = bih[n] + bhh[n];
#pragma unroll 8
    for (int k = 0; k < 128; k += 4) {
        float4 x4 = *(const float4*)(xr + k);
        float4 w4 = *(const float4*)(wr + k);
        acc += x4.x * w4.x + x4.y * w4.y + x4.z * w4.z + x4.w * w4.w;
    }
    s0[(size_t)b * 4096 + n] = acc;
}

// W0[n][0:64] = W_ih0[n][128:192] (y-feedback cols), W0[n][64:1088] = W_hh0[n][:]
__global__ __launch_bounds__(256) void build_w0(
    const float* __restrict__ wih, const float* __restrict__ whh,
    unsigned short* __restrict__ w0)
{
    int idx = blockIdx.x * 256 + threadIdx.x;   // 4096*272 exact
    int n = idx / 272;
    int c = (idx - n * 272) * 4;
    float4 v;
    if (c < 64) v = *(const float4*)(wih + (size_t)n * 192 + 128 + c);
    else        v = *(const float4*)(whh + (size_t)n * 1024 + (c - 64));
    ushort4 o;
    o.x = f2bf(v.x); o.y = f2bf(v.y); o.z = f2bf(v.z); o.w = f2bf(v.w);
    *(ushort4*)(w0 + (size_t)n * KA + c) = o;
}

// W1[n][0:1024] = W_ih1[n][:], W1[n][1024:2048] = W_hh1[n][:]
__global__ __launch_bounds__(256) void build_w1(
    const float* __restrict__ wih, const float* __restrict__ whh,
    unsigned short* __restrict__ w1)
{
    int idx = blockIdx.x * 256 + threadIdx.x;   // 4096*512 exact
    int n = idx >> 9;
    int c = (idx & 511) * 4;
    float4 v;
    if (c < 1024) v = *(const float4*)(wih + (size_t)n * 1024 + c);
    else          v = *(const float4*)(whh + (size_t)n * 1024 + (c - 1024));
    ushort4 o;
    o.x = f2bf(v.x); o.y = f2bf(v.y); o.z = f2bf(v.z); o.w = f2bf(v.w);
    *(ushort4*)(w1 + (size_t)n * KB + c) = o;
}

__global__ __launch_bounds__(256) void build_b1(
    const float* __restrict__ a, const float* __restrict__ b, float* __restrict__ o)
{
    int i = blockIdx.x * 256 + threadIdx.x;
    o[i] = a[i] + b[i];
}

extern "C" void kernel_launch(void* const* d_in, const int* in_sizes, int n_in,
                              void* d_out, int out_size, void* d_ws, size_t ws_size,
                              hipStream_t stream)
{
    (void)in_sizes; (void)n_in; (void)out_size; (void)ws_size;
    const float* static_in = (const float*)d_in[0];
    const float* Wih0 = (const float*)d_in[1];
    const float* Whh0 = (const float*)d_in[2];
    const float* bih0 = (const float*)d_in[3];
    const float* bhh0 = (const float*)d_in[4];
    const float* Wih1 = (const float*)d_in[5];
    const float* Whh1 = (const float*)d_in[6];
    const float* bih1 = (const float*)d_in[7];
    const float* bhh1 = (const float*)d_in[8];
    const float* Wout = (const float*)d_in[9];
    const float* bout = (const float*)d_in[10];
    float* out = (float*)d_out;

    char* p = (char*)d_ws;
    size_t off = 0;
    auto take = [&](size_t n) { char* r = p + off; off += (n + 255) & ~(size_t)255; return r; };

    unsigned short* W0  = (unsigned short*)take((size_t)4096 * KA * 2);
    unsigned short* W1  = (unsigned short*)take((size_t)4096 * KB * 2);
    float*          B1b = (float*)take(4096 * 4);
    float*          S0  = (float*)take((size_t)BATCH * 4096 * 4);
    float*          H2f = (float*)take((size_t)BATCH * HID * 4);
    float*          C1  = (float*)take((size_t)BATCH * HID * 4);
    float*          C2  = (float*)take((size_t)BATCH * HID * 4);
    unsigned short* X0a = (unsigned short*)take((size_t)BATCH * KA * 2);
    unsigned short* X0b = (unsigned short*)take((size_t)BATCH * KA * 2);
    unsigned short* X1a = (unsigned short*)take((size_t)BATCH * KB * 2);
    unsigned short* X1b = (unsigned short*)take((size_t)BATCH * KB * 2);
    // total ~186 MiB

    hipMemsetAsync(C1, 0, (size_t)BATCH * HID * 4, stream);
    hipMemsetAsync(C2, 0, (size_t)BATCH * HID * 4, stream);
    hipMemsetAsync(X0a, 0, (size_t)BATCH * KA * 2, stream);   // y0 = h1_0 = 0
    hipMemsetAsync(X1a, 0, (size_t)BATCH * KB * 2, stream);   // h2_0 = 0

    build_w0<<<4352, 256, 0, stream>>>(Wih0, Whh0, W0);
    build_w1<<<8192, 256, 0, stream>>>(Wih1, Whh1, W1);
    build_b1<<<16, 256, 0, stream>>>(bih1, bhh1, B1b);
    s0_gemm<<<65536, 256, 0, stream>>>(static_in, Wih0, bih0, bhh0, S0);

    dim3 grid(32, 32);
    for (int t = 0; t < TSTEPS; ++t) {
        unsigned short* X0c = (t & 1) ? X0b : X0a;
        unsigned short* X0n = (t & 1) ? X0a : X0b;
        unsigned short* X1c = (t & 1) ? X1b : X1a;
        unsigned short* X1n = (t & 1) ? X1a : X1b;
        // layer 0: gates = X0c @ W0^T + S0[b]; h1 -> X1c[:,0:1024] and X0n[:,64:1088]
        lstm_gate_gemm<<<grid, 256, 0, stream>>>(X0c, KA, W0, S0, 4096, C1,
                                                 X1c, KB, 0, X0n, KA, 64, nullptr);
        // layer 1: gates = X1c @ W1^T + b1; h2 -> X1n[:,1024:2048] (bf16) and H2f (fp32)
        lstm_gate_gemm<<<grid, 256, 0, stream>>>(X1c, KB, W1, B1b, 0, C2,
                                                 X1n, KB, 1024, nullptr, 0, 0, H2f);
        // y_t = H2f @ Wout^T + bout -> out[:,t,:] and X0n[:,0:64]
        out_gemm<<<1024, 256, 0, stream>>>(H2f, Wout, bout, out + t * NOUT, X0n);
    }
}

// Round 2
// 4988.029 us; speedup vs baseline: 1.7635x; 1.7635x over previous
//
#include <hip/hip_runtime.h>

#define BATCH  4096
#define HID    1024
#define NOUT   64
#define TSTEPS 25
#define KA     1088   // 64 (y_prev) + 1024 (h1)
#define KB     2048   // 1024 (h1) + 1024 (h2)
#define LDY    1600   // TSTEPS * NOUT

typedef __attribute__((ext_vector_type(8))) __bf16 bf16x8;
typedef __attribute__((ext_vector_type(4))) float  floatx4;

__device__ __forceinline__ unsigned short f2bf(float f) {
    union { float f; unsigned u; } v; v.f = f;
    unsigned r = v.u + 0x7fffu + ((v.u >> 16) & 1u);
    return (unsigned short)(r >> 16);
}
__device__ __forceinline__ float sigmf(float x) { return 1.0f / (1.0f + __expf(-x)); }
__device__ __forceinline__ float tanh_fast(float x) {
    float ax = fabsf(x);
    float e  = __expf(-2.0f * ax);
    float t  = (1.0f - e) / (1.0f + e);
    return copysignf(t, x);
}

#define GLDS16(gp, lp) __builtin_amdgcn_global_load_lds( \
    (const __attribute__((address_space(1))) void*)(gp), \
    (__attribute__((address_space(3))) void*)(lp), 16, 0, 0)

// Fused GEMM + LSTM cell.
// G = X[4096,K] @ W[4096,K]^T (W rows gate-major: gate*HID + j), then per (b,j):
// gates = G + ginit[b*gstride + j*4 + gate]   (gate-interleaved float4 layout!),
// c' = sig(f)*c + sig(i)*tanh(g); h = sig(o)*tanh(c'); h -> d1/d2 (bf16), dfp (fp32).
// Tile 128x128, 4 waves 2x2, mfma 16x16x32 bf16, BK=32, global_load_lds staging.
// N-mapping gate-minor: n_local = 4*jj + gate -> wave tile owns 16 j with all 4 gates.
__global__ __launch_bounds__(256, 3) void lstm_gate_gemm(
    const unsigned short* __restrict__ X, int K,
    const unsigned short* __restrict__ W,
    const float* __restrict__ ginit, int gstride,
    float* __restrict__ cell,
    unsigned short* __restrict__ d1, int ld1, int off1,
    unsigned short* __restrict__ d2, int ld2, int off2,
    float* __restrict__ dfp)
{
    __shared__ __align__(16) char smem[16384];   // staging A(8K)+B(8K); reused as epilogue scratch

    const int tid  = threadIdx.x;
    const int lane = tid & 63;
    const int w    = tid >> 6;
    const int q    = lane >> 4;
    const int lr   = lane & 15;
    const int wm   = w >> 1;
    const int wn   = w & 1;
    const int m0   = blockIdx.x * 128;
    const int j0   = blockIdx.y * 32;

    // staging: slot s (16B) holds tile-row s>>2, k-group (s&3)^((row>>1)&3) (xor swizzle)
    const unsigned short* srcA[2];
    const unsigned short* srcB[2];
    char* ldsA[2];
    char* ldsB[2];
#pragma unroll
    for (int e = 0; e < 2; ++e) {
        int s   = e * 256 + tid;
        int row = s >> 2;
        int kg  = (s & 3) ^ ((row >> 1) & 3);
        srcA[e] = X + (size_t)(m0 + row) * K + kg * 8;
        int jj = row >> 2, gate = row & 3;
        srcB[e] = W + (size_t)(gate * HID + j0 + jj) * K + kg * 8;
        ldsA[e] = smem + (e * 256 + w * 64) * 16;
        ldsB[e] = smem + 8192 + (e * 256 + w * 64) * 16;
    }

    // fragment LDS offsets (same swizzle)
    unsigned offA[4], offB[4];
#pragma unroll
    for (int i = 0; i < 4; ++i) {
        int ra = wm * 64 + i * 16 + lr;
        offA[i] = (unsigned)((ra * 4 + (q ^ ((ra >> 1) & 3))) * 16);
        int rb = wn * 64 + i * 16 + lr;
        offB[i] = (unsigned)(8192 + (rb * 4 + (q ^ ((rb >> 1) & 3))) * 16);
    }

    floatx4 acc[4][4];
#pragma unroll
    for (int i = 0; i < 4; ++i)
#pragma unroll
        for (int j = 0; j < 4; ++j)
            acc[i][j] = floatx4{0.f, 0.f, 0.f, 0.f};

    const int kiters = K >> 5;
    for (int kt = 0; kt < kiters; ++kt) {
        const int koff = kt * 32;
#pragma unroll
        for (int e = 0; e < 2; ++e) {
            GLDS16(srcA[e] + koff, ldsA[e]);
            GLDS16(srcB[e] + koff, ldsB[e]);
        }
        __syncthreads();
        bf16x8 av[4], bv[4];
#pragma unroll
        for (int i = 0; i < 4; ++i) av[i] = *(const bf16x8*)(smem + offA[i]);
#pragma unroll
        for (int j = 0; j < 4; ++j) bv[j] = *(const bf16x8*)(smem + offB[j]);
#pragma unroll
        for (int i = 0; i < 4; ++i)
#pragma unroll
            for (int j = 0; j < 4; ++j)
                acc[i][j] = __builtin_amdgcn_mfma_f32_16x16x32_bf16(av[i], bv[j], acc[i][j], 0, 0, 0);
        __syncthreads();
    }

    // ---- epilogue: per-wave LDS transpose of 16x64 sub-tiles, then cell update
    const int jg = j0 + wn * 16 + lr;            // hidden index for read phase
    float* scratch = (float*)(void*)smem + w * (16 * 64);

#pragma unroll
    for (int i = 0; i < 4; ++i) {
        __syncthreads();
#pragma unroll
        for (int j = 0; j < 4; ++j)
#pragma unroll
            for (int r = 0; r < 4; ++r)
                scratch[(q * 4 + r) * 64 + j * 16 + lr] = acc[i][j][r];  // C/D: row=q*4+r, col=lr
        __syncthreads();
#pragma unroll
        for (int p = 0; p < 4; ++p) {
            int row = q + p * 4;
            const float4 g = *(const float4*)(scratch + row * 64 + lr * 4);  // (i,f,g,o)
            int b = m0 + wm * 64 + i * 16 + row;
            const float4 gi = *(const float4*)(ginit + (size_t)b * gstride + (size_t)jg * 4);
            float iv = sigmf(g.x + gi.x);
            float fv = sigmf(g.y + gi.y);
            float gv = tanh_fast(g.z + gi.z);
            float ov = sigmf(g.w + gi.w);
            size_t ci = (size_t)b * HID + jg;
            float cn = fv * cell[ci] + iv * gv;
            cell[ci] = cn;
            float hv = ov * tanh_fast(cn);
            unsigned short hb = f2bf(hv);
            d1[(size_t)b * ld1 + off1 + jg] = hb;
            if (d2)  d2[(size_t)b * ld2 + off2 + jg] = hb;
            if (dfp) dfp[(size_t)b * HID + jg] = hv;
        }
    }
}

// ---- S0 = static @ W_ih0[:, :128]^T + b0, fp32, gate-interleaved output [b][j*4+gate]
// WT4 layout: wt4[k*4096 + j*4 + gate] = W_ih0[gate*1024+j][k], k<128
__global__ __launch_bounds__(256) void s0_gemm_tiled(
    const float* __restrict__ stat, const float* __restrict__ wt4,
    const float* __restrict__ bias4, float* __restrict__ s0)
{
    __shared__ float xl[32 * 128];   // 16 KB: 32 batch rows of static input
    const int tid = threadIdx.x;
    const int j0 = blockIdx.x * 64;
    const int b0 = blockIdx.y * 32;
#pragma unroll
    for (int r = 0; r < 4; ++r) {
        int f4 = r * 256 + tid;
        *(float4*)(xl + f4 * 4) = *(const float4*)(stat + (size_t)b0 * 128 + f4 * 4);
    }
    __syncthreads();
    const int j  = j0 + (tid & 63);
    const int wv = tid >> 6;
    float4 acc[8];
#pragma unroll
    for (int bb = 0; bb < 8; ++bb) acc[bb] = float4{0.f, 0.f, 0.f, 0.f};
#pragma unroll 4
    for (int k = 0; k < 128; ++k) {
        float4 w4 = *(const float4*)(wt4 + (size_t)k * 4096 + j * 4);
#pragma unroll
        for (int bb = 0; bb < 8; ++bb) {
            float xv = xl[(wv * 8 + bb) * 128 + k];
            acc[bb].x += xv * w4.x; acc[bb].y += xv * w4.y;
            acc[bb].z += xv * w4.z; acc[bb].w += xv * w4.w;
        }
    }
    float4 bi = *(const float4*)(bias4 + (size_t)j * 4);
#pragma unroll
    for (int bb = 0; bb < 8; ++bb) {
        int b = b0 + wv * 8 + bb;
        float4 o;
        o.x = acc[bb].x + bi.x; o.y = acc[bb].y + bi.y;
        o.z = acc[bb].z + bi.z; o.w = acc[bb].w + bi.w;
        *(float4*)(s0 + (size_t)b * 4096 + j * 4) = o;
    }
}

// y = h2_f32 @ Wout^T + bout (fp32); WoutT layout wt[k*64+o]; h2 staged in LDS.
__global__ __launch_bounds__(256) void out_gemm(
    const float* __restrict__ h2, const float* __restrict__ wt,
    const float* __restrict__ bout, float* __restrict__ y,
    unsigned short* __restrict__ xn)
{
    __shared__ float hl[8 * 1024];   // 32 KB: 8 h2 rows
    const int tid = threadIdx.x;
    const int b0 = blockIdx.x * 8;
#pragma unroll
    for (int r = 0; r < 8; ++r) {
        int f4 = r * 256 + tid;
        *(float4*)(hl + f4 * 4) = *(const float4*)(h2 + (size_t)b0 * 1024 + f4 * 4);
    }
    __syncthreads();
    const int o  = tid & 63;
    const int wv = tid >> 6;
    float acc0 = 0.f, acc1 = 0.f;
#pragma unroll 8
    for (int k = 0; k < 1024; ++k) {
        float wvv = wt[k * 64 + o];
        acc0 += hl[(wv * 2 + 0) * 1024 + k] * wvv;
        acc1 += hl[(wv * 2 + 1) * 1024 + k] * wvv;
    }
    float bo = bout[o];
    int b = b0 + wv * 2;
    float y0 = acc0 + bo, y1 = acc1 + bo;
    y[(size_t)b * LDY + o] = y0;
    y[(size_t)(b + 1) * LDY + o] = y1;
    xn[(size_t)b * KA + o] = f2bf(y0);
    xn[(size_t)(b + 1) * KA + o] = f2bf(y1);
}

// WT4[k*4096 + j*4 + gate] = W_ih0[(gate*1024+j)*192 + k]  (k < 128)
__global__ void build_wt0(const float* __restrict__ wih, float* __restrict__ wt4)
{
    int idx = blockIdx.x * 256 + threadIdx.x;   // 524288
    int gate = idx & 3, j = (idx >> 2) & 1023, k = idx >> 12;
    wt4[idx] = wih[(size_t)(gate * 1024 + j) * 192 + k];
}

// WoutT[k*64+o] = Wout[o*1024+k]
__global__ void build_woutT(const float* __restrict__ wout, float* __restrict__ wt)
{
    int idx = blockIdx.x * 256 + threadIdx.x;   // 65536
    int o = idx & 63, k = idx >> 6;
    wt[idx] = wout[(size_t)o * 1024 + k];
}

// interleaved bias: out[j*4+gate] = a[gate*1024+j] + b[gate*1024+j]
__global__ void build_bias(const float* __restrict__ a, const float* __restrict__ b,
                           float* __restrict__ o)
{
    int idx = blockIdx.x * 256 + threadIdx.x;   // 4096
    int gate = idx & 3, j = idx >> 2;
    int n = gate * 1024 + j;
    o[idx] = a[n] + b[n];
}

// W0[n][0:64] = W_ih0[n][128:192] (y-feedback cols), W0[n][64:1088] = W_hh0[n][:]
__global__ __launch_bounds__(256) void build_w0(
    const float* __restrict__ wih, const float* __restrict__ whh,
    unsigned short* __restrict__ w0)
{
    int idx = blockIdx.x * 256 + threadIdx.x;   // 4096*272 exact
    int n = idx / 272;
    int c = (idx - n * 272) * 4;
    float4 v;
    if (c < 64) v = *(const float4*)(wih + (size_t)n * 192 + 128 + c);
    else        v = *(const float4*)(whh + (size_t)n * 1024 + (c - 64));
    ushort4 o;
    o.x = f2bf(v.x); o.y = f2bf(v.y); o.z = f2bf(v.z); o.w = f2bf(v.w);
    *(ushort4*)(w0 + (size_t)n * KA + c) = o;
}

// W1[n][0:1024] = W_ih1[n][:], W1[n][1024:2048] = W_hh1[n][:]
__global__ __launch_bounds__(256) void build_w1(
    const float* __restrict__ wih, const float* __restrict__ whh,
    unsigned short* __restrict__ w1)
{
    int idx = blockIdx.x * 256 + threadIdx.x;   // 4096*512 exact
    int n = idx >> 9;
    int c = (idx & 511) * 4;
    float4 v;
    if (c < 1024) v = *(const float4*)(wih + (size_t)n * 1024 + c);
    else          v = *(const float4*)(whh + (size_t)n * 1024 + (c - 1024));
    ushort4 o;
    o.x = f2bf(v.x); o.y = f2bf(v.y); o.z = f2bf(v.z); o.w = f2bf(v.w);
    *(ushort4*)(w1 + (size_t)n * KB + c) = o;
}

extern "C" void kernel_launch(void* const* d_in, const int* in_sizes, int n_in,
                              void* d_out, int out_size, void* d_ws, size_t ws_size,
                              hipStream_t stream)
{
    (void)in_sizes; (void)n_in; (void)out_size; (void)ws_size;
    const float* static_in = (const float*)d_in[0];
    const float* Wih0 = (const float*)d_in[1];
    const float* Whh0 = (const float*)d_in[2];
    const float* bih0 = (const float*)d_in[3];
    const float* bhh0 = (const float*)d_in[4];
    const float* Wih1 = (const float*)d_in[5];
    const float* Whh1 = (const float*)d_in[6];
    const float* bih1 = (const float*)d_in[7];
    const float* bhh1 = (const float*)d_in[8];
    const float* Wout = (const float*)d_in[9];
    const float* bout = (const float*)d_in[10];
    float* out = (float*)d_out;

    char* p = (char*)d_ws;
    size_t off = 0;
    auto take = [&](size_t n) { char* r = p + off; off += (n + 255) & ~(size_t)255; return r; };

    unsigned short* W0   = (unsigned short*)take((size_t)4096 * KA * 2);
    unsigned short* W1   = (unsigned short*)take((size_t)4096 * KB * 2);
    float*          B1b  = (float*)take(4096 * 4);
    float*          B0b  = (float*)take(4096 * 4);
    float*          WT0  = (float*)take((size_t)128 * 4096 * 4);
    float*          WoT  = (float*)take((size_t)1024 * 64 * 4);
    float*          S0   = (float*)take((size_t)BATCH * 4096 * 4);
    float*          H2f  = (float*)take((size_t)BATCH * HID * 4);
    float*          C1   = (float*)take((size_t)BATCH * HID * 4);
    float*          C2   = (float*)take((size_t)BATCH * HID * 4);
    unsigned short* X0a  = (unsigned short*)take((size_t)BATCH * KA * 2);
    unsigned short* X0b  = (unsigned short*)take((size_t)BATCH * KA * 2);
    unsigned short* X1a  = (unsigned short*)take((size_t)BATCH * KB * 2);
    unsigned short* X1b  = (unsigned short*)take((size_t)BATCH * KB * 2);
    // total ~190 MiB

    hipMemsetAsync(C1, 0, (size_t)BATCH * HID * 4, stream);
    hipMemsetAsync(C2, 0, (size_t)BATCH * HID * 4, stream);
    hipMemsetAsync(X0a, 0, (size_t)BATCH * KA * 2, stream);   // y0 = h1_0 = 0
    hipMemsetAsync(X1a, 0, (size_t)BATCH * KB * 2, stream);   // h2_0 = 0

    build_w0<<<4352, 256, 0, stream>>>(Wih0, Whh0, W0);
    build_w1<<<8192, 256, 0, stream>>>(Wih1, Whh1, W1);
    build_wt0<<<2048, 256, 0, stream>>>(Wih0, WT0);
    build_woutT<<<256, 256, 0, stream>>>(Wout, WoT);
    build_bias<<<16, 256, 0, stream>>>(bih0, bhh0, B0b);
    build_bias<<<16, 256, 0, stream>>>(bih1, bhh1, B1b);
    s0_gemm_tiled<<<dim3(16, 128), 256, 0, stream>>>(static_in, WT0, B0b, S0);

    dim3 grid(32, 32);
    for (int t = 0; t < TSTEPS; ++t) {
        unsigned short* X0c = (t & 1) ? X0b : X0a;
        unsigned short* X0n = (t & 1) ? X0a : X0b;
        unsigned short* X1c = (t & 1) ? X1b : X1a;
        unsigned short* X1n = (t & 1) ? X1a : X1b;
        // layer 0: gates = X0c @ W0^T + S0[b]; h1 -> X1c[:,0:1024] and X0n[:,64:1088]
        lstm_gate_gemm<<<grid, 256, 0, stream>>>(X0c, KA, W0, S0, 4096, C1,
                                                 X1c, KB, 0, X0n, KA, 64, nullptr);
        // layer 1: gates = X1c @ W1^T + b1 (interleaved); h2 -> X1n[:,1024:2048] + H2f
        lstm_gate_gemm<<<grid, 256, 0, stream>>>(X1c, KB, W1, B1b, 0, C2,
                                                 X1n, KB, 1024, nullptr, 0, 0, H2f);
        // y_t = H2f @ WoutT + bout -> out[:,t,:] and X0n[:,0:64]
        out_gemm<<<512, 256, 0, stream>>>(H2f, WoT, bout, out + t * NOUT, X0n);
    }
}

// Round 4
// 4629.307 us; speedup vs baseline: 1.9002x; 1.0775x over previous
//
#include <hip/hip_runtime.h>

#define BATCH  4096
#define HID    1024
#define NOUT   64
#define TSTEPS 25
#define KA     1088   // 64 (y_prev) + 1024 (h1)
#define KB     2048   // 1024 (h1) + 1024 (h2)
#define LDY    1600   // TSTEPS * NOUT

typedef __attribute__((ext_vector_type(8))) __bf16 bf16x8;
typedef __attribute__((ext_vector_type(4))) float  floatx4;

__device__ __forceinline__ unsigned short f2bf(float f) {
    union { float f; unsigned u; } v; v.f = f;
    unsigned r = v.u + 0x7fffu + ((v.u >> 16) & 1u);
    return (unsigned short)(r >> 16);
}
__device__ __forceinline__ float rcpf(float x) { return __builtin_amdgcn_rcpf(x); }
__device__ __forceinline__ float sigmf(float x) { return rcpf(1.0f + __expf(-x)); }
__device__ __forceinline__ float tanh_fast(float x) {
    float ax = fabsf(x);
    float e  = __expf(-2.0f * ax);
    float t  = (1.0f - e) * rcpf(1.0f + e);
    return copysignf(t, x);
}

#define GLDS16(gp, lp) __builtin_amdgcn_global_load_lds( \
    (const __attribute__((address_space(1))) void*)(gp), \
    (__attribute__((address_space(3))) void*)(lp), 16, 0, 0)

// Fused GEMM + LSTM cell, v2b: block tile 256(M)x128(N), 4 waves 2x2,
// wave tile 128x64 (acc[8][4]) -> 32 MFMA : 12 ds_read_b128 per BK=32.
// Epilogue slabs are barrier-fenced (v2 regression: removing them let the
// compiler reorder scalar ds_writes vs float4 ds_reads -> garbage).
// G = X[4096,K] @ W[4096,K]^T (W rows gate-major: gate*HID + j), then per (b,j):
// gates = G + ginit[b*gstride + j*4 + gate]   (gate-interleaved float4 layout),
// c' = sig(f)*c + sig(i)*tanh(g); h = sig(o)*tanh(c'); h -> d1/d2 (bf16), dfp (fp32).
__global__ __launch_bounds__(256, 2) void lstm_gate_gemm(
    const unsigned short* __restrict__ X, int K,
    const unsigned short* __restrict__ W,
    const float* __restrict__ ginit, int gstride,
    float* __restrict__ cell,
    unsigned short* __restrict__ d1, int ld1, int off1,
    unsigned short* __restrict__ d2, int ld2, int off2,
    float* __restrict__ dfp)
{
    __shared__ __align__(16) char smem[24576];   // A stage 16K (slots 0..1023) + B stage 8K (1024..1535)

    const int tid  = threadIdx.x;
    const int lane = tid & 63;
    const int w    = tid >> 6;
    const int q    = lane >> 4;
    const int lr   = lane & 15;
    const int wm   = w >> 1;            // row half (128 rows each)
    const int wn   = w & 1;             // col half (64 cols each)
    const int m0   = blockIdx.x * 256;
    const int j0   = blockIdx.y * 32;

    // staging: slot s (16B) holds tile-row s>>2 (A: 256 rows, B: 128 rows),
    // k-group (s&3)^((row>>1)&3) (xor swizzle). 6 slots per thread.
    const unsigned short* srcS[6];
    char* ldsS[6];
#pragma unroll
    for (int e = 0; e < 6; ++e) {
        int s = e * 256 + tid;
        if (s < 1024) {
            int row = s >> 2;
            int kg  = (s & 3) ^ ((row >> 1) & 3);
            srcS[e] = X + (size_t)(m0 + row) * K + kg * 8;
        } else {
            int t   = s - 1024;
            int row = t >> 2;
            int kg  = (t & 3) ^ ((row >> 1) & 3);
            int jj = row >> 2, gate = row & 3;
            srcS[e] = W + (size_t)(gate * HID + j0 + jj) * K + kg * 8;
        }
        ldsS[e] = smem + (e * 256 + w * 64) * 16;
    }

    // fragment LDS offsets (same swizzle)
    unsigned offA[8], offB[4];
#pragma unroll
    for (int i = 0; i < 8; ++i) {
        int ra = wm * 128 + i * 16 + lr;                 // 0..255
        offA[i] = (unsigned)((ra * 4 + (q ^ ((ra >> 1) & 3))) * 16);
    }
#pragma unroll
    for (int j = 0; j < 4; ++j) {
        int rb = wn * 64 + j * 16 + lr;                  // 0..127
        offB[j] = (unsigned)(16384 + (rb * 4 + (q ^ ((rb >> 1) & 3))) * 16);
    }

    floatx4 acc[8][4];
#pragma unroll
    for (int i = 0; i < 8; ++i)
#pragma unroll
        for (int j = 0; j < 4; ++j)
            acc[i][j] = floatx4{0.f, 0.f, 0.f, 0.f};

    const int kiters = K >> 5;
    for (int kt = 0; kt < kiters; ++kt) {
        const int koff = kt * 32;
#pragma unroll
        for (int e = 0; e < 6; ++e)
            GLDS16(srcS[e] + koff, ldsS[e]);
        __syncthreads();
        bf16x8 bv[4];
#pragma unroll
        for (int j = 0; j < 4; ++j) bv[j] = *(const bf16x8*)(smem + offB[j]);
#pragma unroll
        for (int i = 0; i < 8; ++i) {
            bf16x8 av = *(const bf16x8*)(smem + offA[i]);
#pragma unroll
            for (int j = 0; j < 4; ++j)
                acc[i][j] = __builtin_amdgcn_mfma_f32_16x16x32_bf16(av, bv[j], acc[i][j], 0, 0, 0);
        }
        __syncthreads();
    }

    // ---- epilogue: per-wave LDS transpose of 16x64 slabs, then cell update.
    // Barriers fence write-phase vs read-phase (compiler memory ordering —
    // scalar float stores vs float4 loads are not TBAA-ordered without them).
    const int jg = j0 + wn * 16 + lr;
    float* scratch = (float*)(void*)smem + w * 1024;     // 4 KB per wave, wave-private

#pragma unroll
    for (int i = 0; i < 8; ++i) {
        __syncthreads();
#pragma unroll
        for (int j = 0; j < 4; ++j)
#pragma unroll
            for (int r = 0; r < 4; ++r)
                scratch[(q * 4 + r) * 64 + j * 16 + lr] = acc[i][j][r];  // C/D: row=q*4+r, col=lr
        __syncthreads();
#pragma unroll
        for (int p = 0; p < 4; ++p) {
            int row = q + p * 4;
            const float4 g = *(const float4*)(scratch + row * 64 + lr * 4);  // (i,f,g,o)
            int b = m0 + wm * 128 + i * 16 + row;
            const float4 gi = *(const float4*)(ginit + (size_t)b * gstride + (size_t)jg * 4);
            float iv = sigmf(g.x + gi.x);
            float fv = sigmf(g.y + gi.y);
            float gv = tanh_fast(g.z + gi.z);
            float ov = sigmf(g.w + gi.w);
            size_t ci = (size_t)b * HID + jg;
            float cn = fv * cell[ci] + iv * gv;
            cell[ci] = cn;
            float hv = ov * tanh_fast(cn);
            unsigned short hb = f2bf(hv);
            d1[(size_t)b * ld1 + off1 + jg] = hb;
            if (d2)  d2[(size_t)b * ld2 + off2 + jg] = hb;
            if (dfp) dfp[(size_t)b * HID + jg] = hv;
        }
    }
}

// ---- S0 = static @ W_ih0[:, :128]^T + b0, fp32, gate-interleaved output [b][j*4+gate]
// WT4 layout: wt4[k*4096 + j*4 + gate] = W_ih0[gate*1024+j][k], k<128
__global__ __launch_bounds__(256) void s0_gemm_tiled(
    const float* __restrict__ stat, const float* __restrict__ wt4,
    const float* __restrict__ bias4, float* __restrict__ s0)
{
    __shared__ float xl[32 * 128];   // 16 KB: 32 batch rows of static input
    const int tid = threadIdx.x;
    const int j0 = blockIdx.x * 64;
    const int b0 = blockIdx.y * 32;
#pragma unroll
    for (int r = 0; r < 4; ++r) {
        int f4 = r * 256 + tid;
        *(float4*)(xl + f4 * 4) = *(const float4*)(stat + (size_t)b0 * 128 + f4 * 4);
    }
    __syncthreads();
    const int j  = j0 + (tid & 63);
    const int wv = tid >> 6;
    float4 acc[8];
#pragma unroll
    for (int bb = 0; bb < 8; ++bb) acc[bb] = float4{0.f, 0.f, 0.f, 0.f};
#pragma unroll 4
    for (int k = 0; k < 128; ++k) {
        float4 w4 = *(const float4*)(wt4 + (size_t)k * 4096 + j * 4);
#pragma unroll
        for (int bb = 0; bb < 8; ++bb) {
            float xv = xl[(wv * 8 + bb) * 128 + k];
            acc[bb].x += xv * w4.x; acc[bb].y += xv * w4.y;
            acc[bb].z += xv * w4.z; acc[bb].w += xv * w4.w;
        }
    }
    float4 bi = *(const float4*)(bias4 + (size_t)j * 4);
#pragma unroll
    for (int bb = 0; bb < 8; ++bb) {
        int b = b0 + wv * 8 + bb;
        float4 o;
        o.x = acc[bb].x + bi.x; o.y = acc[bb].y + bi.y;
        o.z = acc[bb].z + bi.z; o.w = acc[bb].w + bi.w;
        *(float4*)(s0 + (size_t)b * 4096 + j * 4) = o;
    }
}

// y = h2_f32 @ Wout^T + bout (fp32); WoutT layout wt[k*64+o]; h2 staged in LDS.
__global__ __launch_bounds__(256) void out_gemm(
    const float* __restrict__ h2, const float* __restrict__ wt,
    const float* __restrict__ bout, float* __restrict__ y,
    unsigned short* __restrict__ xn)
{
    __shared__ float hl[8 * 1024];   // 32 KB: 8 h2 rows
    const int tid = threadIdx.x;
    const int b0 = blockIdx.x * 8;
#pragma unroll
    for (int r = 0; r < 8; ++r) {
        int f4 = r * 256 + tid;
        *(float4*)(hl + f4 * 4) = *(const float4*)(h2 + (size_t)b0 * 1024 + f4 * 4);
    }
    __syncthreads();
    const int o  = tid & 63;
    const int wv = tid >> 6;
    float acc0 = 0.f, acc1 = 0.f;
#pragma unroll 8
    for (int k = 0; k < 1024; ++k) {
        float wvv = wt[k * 64 + o];
        acc0 += hl[(wv * 2 + 0) * 1024 + k] * wvv;
        acc1 += hl[(wv * 2 + 1) * 1024 + k] * wvv;
    }
    float bo = bout[o];
    int b = b0 + wv * 2;
    float y0 = acc0 + bo, y1 = acc1 + bo;
    y[(size_t)b * LDY + o] = y0;
    y[(size_t)(b + 1) * LDY + o] = y1;
    xn[(size_t)b * KA + o] = f2bf(y0);
    xn[(size_t)(b + 1) * KA + o] = f2bf(y1);
}

// WT4[k*4096 + j*4 + gate] = W_ih0[(gate*1024+j)*192 + k]  (k < 128)
__global__ void build_wt0(const float* __restrict__ wih, float* __restrict__ wt4)
{
    int idx = blockIdx.x * 256 + threadIdx.x;   // 524288
    int gate = idx & 3, j = (idx >> 2) & 1023, k = idx >> 12;
    wt4[idx] = wih[(size_t)(gate * 1024 + j) * 192 + k];
}

// WoutT[k*64+o] = Wout[o*1024+k]
__global__ void build_woutT(const float* __restrict__ wout, float* __restrict__ wt)
{
    int idx = blockIdx.x * 256 + threadIdx.x;   // 65536
    int o = idx & 63, k = idx >> 6;
    wt[idx] = wout[(size_t)o * 1024 + k];
}

// interleaved bias: out[j*4+gate] = a[gate*1024+j] + b[gate*1024+j]
__global__ void build_bias(const float* __restrict__ a, const float* __restrict__ b,
                           float* __restrict__ o)
{
    int idx = blockIdx.x * 256 + threadIdx.x;   // 4096
    int gate = idx & 3, j = idx >> 2;
    int n = gate * 1024 + j;
    o[idx] = a[n] + b[n];
}

// W0[n][0:64] = W_ih0[n][128:192] (y-feedback cols), W0[n][64:1088] = W_hh0[n][:]
__global__ __launch_bounds__(256) void build_w0(
    const float* __restrict__ wih, const float* __restrict__ whh,
    unsigned short* __restrict__ w0)
{
    int idx = blockIdx.x * 256 + threadIdx.x;   // 4096*272 exact
    int n = idx / 272;
    int c = (idx - n * 272) * 4;
    float4 v;
    if (c < 64) v = *(const float4*)(wih + (size_t)n * 192 + 128 + c);
    else        v = *(const float4*)(whh + (size_t)n * 1024 + (c - 64));
    ushort4 o;
    o.x = f2bf(v.x); o.y = f2bf(v.y); o.z = f2bf(v.z); o.w = f2bf(v.w);
    *(ushort4*)(w0 + (size_t)n * KA + c) = o;
}

// W1[n][0:1024] = W_ih1[n][:], W1[n][1024:2048] = W_hh1[n][:]
__global__ __launch_bounds__(256) void build_w1(
    const float* __restrict__ wih, const float* __restrict__ whh,
    unsigned short* __restrict__ w1)
{
    int idx = blockIdx.x * 256 + threadIdx.x;   // 4096*512 exact
    int n = idx >> 9;
    int c = (idx & 511) * 4;
    float4 v;
    if (c < 1024) v = *(const float4*)(wih + (size_t)n * 1024 + c);
    else          v = *(const float4*)(whh + (size_t)n * 1024 + (c - 1024));
    ushort4 o;
    o.x = f2bf(v.x); o.y = f2bf(v.y); o.z = f2bf(v.z); o.w = f2bf(v.w);
    *(ushort4*)(w1 + (size_t)n * KB + c) = o;
}

extern "C" void kernel_launch(void* const* d_in, const int* in_sizes, int n_in,
                              void* d_out, int out_size, void* d_ws, size_t ws_size,
                              hipStream_t stream)
{
    (void)in_sizes; (void)n_in; (void)out_size; (void)ws_size;
    const float* static_in = (const float*)d_in[0];
    const float* Wih0 = (const float*)d_in[1];
    const float* Whh0 = (const float*)d_in[2];
    const float* bih0 = (const float*)d_in[3];
    const float* bhh0 = (const float*)d_in[4];
    const float* Wih1 = (const float*)d_in[5];
    const float* Whh1 = (const float*)d_in[6];
    const float* bih1 = (const float*)d_in[7];
    const float* bhh1 = (const float*)d_in[8];
    const float* Wout = (const float*)d_in[9];
    const float* bout = (const float*)d_in[10];
    float* out = (float*)d_out;

    char* p = (char*)d_ws;
    size_t off = 0;
    auto take = [&](size_t n) { char* r = p + off; off += (n + 255) & ~(size_t)255; return r; };

    unsigned short* W0   = (unsigned short*)take((size_t)4096 * KA * 2);
    unsigned short* W1   = (unsigned short*)take((size_t)4096 * KB * 2);
    float*          B1b  = (float*)take(4096 * 4);
    float*          B0b  = (float*)take(4096 * 4);
    float*          WT0  = (float*)take((size_t)128 * 4096 * 4);
    float*          WoT  = (float*)take((size_t)1024 * 64 * 4);
    float*          S0   = (float*)take((size_t)BATCH * 4096 * 4);
    float*          H2f  = (float*)take((size_t)BATCH * HID * 4);
    float*          C1   = (float*)take((size_t)BATCH * HID * 4);
    float*          C2   = (float*)take((size_t)BATCH * HID * 4);
    unsigned short* X0a  = (unsigned short*)take((size_t)BATCH * KA * 2);
    unsigned short* X0b  = (unsigned short*)take((size_t)BATCH * KA * 2);
    unsigned short* X1a  = (unsigned short*)take((size_t)BATCH * KB * 2);
    unsigned short* X1b  = (unsigned short*)take((size_t)BATCH * KB * 2);
    // total ~190 MiB

    hipMemsetAsync(C1, 0, (size_t)BATCH * HID * 4, stream);
    hipMemsetAsync(C2, 0, (size_t)BATCH * HID * 4, stream);
    hipMemsetAsync(X0a, 0, (size_t)BATCH * KA * 2, stream);   // y0 = h1_0 = 0
    hipMemsetAsync(X1a, 0, (size_t)BATCH * KB * 2, stream);   // h2_0 = 0

    build_w0<<<4352, 256, 0, stream>>>(Wih0, Whh0, W0);
    build_w1<<<8192, 256, 0, stream>>>(Wih1, Whh1, W1);
    build_wt0<<<2048, 256, 0, stream>>>(Wih0, WT0);
    build_woutT<<<256, 256, 0, stream>>>(Wout, WoT);
    build_bias<<<16, 256, 0, stream>>>(bih0, bhh0, B0b);
    build_bias<<<16, 256, 0, stream>>>(bih1, bhh1, B1b);
    s0_gemm_tiled<<<dim3(16, 128), 256, 0, stream>>>(static_in, WT0, B0b, S0);

    dim3 grid(16, 32);   // 512 blocks = 2 per CU exact
    for (int t = 0; t < TSTEPS; ++t) {
        unsigned short* X0c = (t & 1) ? X0b : X0a;
        unsigned short* X0n = (t & 1) ? X0a : X0b;
        unsigned short* X1c = (t & 1) ? X1b : X1a;
        unsigned short* X1n = (t & 1) ? X1a : X1b;
        // layer 0: gates = X0c @ W0^T + S0[b]; h1 -> X1c[:,0:1024] and X0n[:,64:1088]
        lstm_gate_gemm<<<grid, 256, 0, stream>>>(X0c, KA, W0, S0, 4096, C1,
                                                 X1c, KB, 0, X0n, KA, 64, nullptr);
        // layer 1: gates = X1c @ W1^T + b1 (interleaved); h2 -> X1n[:,1024:2048] + H2f
        lstm_gate_gemm<<<grid, 256, 0, stream>>>(X1c, KB, W1, B1b, 0, C2,
                                                 X1n, KB, 1024, nullptr, 0, 0, H2f);
        // y_t = H2f @ WoutT + bout -> out[:,t,:] and X0n[:,0:64]
        out_gemm<<<512, 256, 0, stream>>>(H2f, WoT, bout, out + t * NOUT, X0n);
    }
}

// Round 5
// 4617.174 us; speedup vs baseline: 1.9052x; 1.0026x over previous
//
#include <hip/hip_runtime.h>

#define BATCH  4096
#define HID    1024
#define NOUT   64
#define TSTEPS 25
#define KA     1088   // 64 (y_prev) + 1024 (h1)
#define KB     2048   // 1024 (h1) + 1024 (h2)
#define LDY    1600   // TSTEPS * NOUT

typedef __attribute__((ext_vector_type(8))) __bf16 bf16x8;
typedef __attribute__((ext_vector_type(4))) float  floatx4;

__device__ __forceinline__ unsigned short f2bf(float f) {
    union { float f; unsigned u; } v; v.f = f;
    unsigned r = v.u + 0x7fffu + ((v.u >> 16) & 1u);
    return (unsigned short)(r >> 16);
}
__device__ __forceinline__ float rcpf(float x) { return __builtin_amdgcn_rcpf(x); }
__device__ __forceinline__ float sigmf(float x) { return rcpf(1.0f + __expf(-x)); }
__device__ __forceinline__ float tanh_fast(float x) {
    float ax = fabsf(x);
    float e  = __expf(-2.0f * ax);
    float t  = (1.0f - e) * rcpf(1.0f + e);
    return copysignf(t, x);
}

#define GLDS16(gp, lp) __builtin_amdgcn_global_load_lds( \
    (const __attribute__((address_space(1))) void*)(gp), \
    (__attribute__((address_space(3))) void*)(lp), 16, 0, 0)

// Fused GEMM + LSTM cell, v3: block tile 256(M)x128(N), 4 waves 2x2,
// wave tile 128x64 (acc[8][4]). DOUBLE-BUFFERED LDS staging, ONE barrier
// per kiter: loads for kt+1 are issued after the barrier and drained at the
// NEXT barrier, so they overlap the full MFMA phase (~1242 cyc >> L2 latency).
// v2's structure drained vmcnt(0) immediately after issue -> 36% of cycles
// were barrier-drain (3750 cyc/kiter measured vs 1242 MFMA).
// G = X[4096,K] @ W[4096,K]^T (W rows gate-major: gate*HID + j), then per (b,j):
// gates = G + ginit[b*gstride + j*4 + gate]   (gate-interleaved float4 layout),
// c' = sig(f)*c + sig(i)*tanh(g); h = sig(o)*tanh(c'); h -> d1/d2 (bf16), dfp (fp32).
__global__ __launch_bounds__(256, 2) void lstm_gate_gemm(
    const unsigned short* __restrict__ X, int K,
    const unsigned short* __restrict__ W,
    const float* __restrict__ ginit, int gstride,
    float* __restrict__ cell,
    unsigned short* __restrict__ d1, int ld1, int off1,
    unsigned short* __restrict__ d2, int ld2, int off2,
    float* __restrict__ dfp)
{
    // buf0: A @0 (16K) + B @16K (8K); buf1: A @24K + B @40K. 48 KB -> 2 blocks/CU.
    __shared__ __align__(16) char smem[49152];

    const int tid  = threadIdx.x;
    const int lane = tid & 63;
    const int w    = tid >> 6;
    const int q    = lane >> 4;
    const int lr   = lane & 15;
    const int wm   = w >> 1;            // row half (128 rows each)
    const int wn   = w & 1;             // col half (64 cols each)
    const int m0   = blockIdx.x * 256;
    const int j0   = blockIdx.y * 32;

    // staging: slot s (16B) holds tile-row s>>2 (A: 256 rows, B: 128 rows),
    // k-group (s&3)^((row>>1)&3) (xor swizzle). 6 slots per thread.
    const unsigned short* srcS[6];
    char* ldsS[6];
#pragma unroll
    for (int e = 0; e < 6; ++e) {
        int s = e * 256 + tid;
        if (s < 1024) {
            int row = s >> 2;
            int kg  = (s & 3) ^ ((row >> 1) & 3);
            srcS[e] = X + (size_t)(m0 + row) * K + kg * 8;
        } else {
            int t   = s - 1024;
            int row = t >> 2;
            int kg  = (t & 3) ^ ((row >> 1) & 3);
            int jj = row >> 2, gate = row & 3;
            srcS[e] = W + (size_t)(gate * HID + j0 + jj) * K + kg * 8;
        }
        ldsS[e] = smem + (e * 256 + w * 64) * 16;
    }

    // fragment LDS offsets within buf0 (same swizzle)
    unsigned offA[8], offB[4];
#pragma unroll
    for (int i = 0; i < 8; ++i) {
        int ra = wm * 128 + i * 16 + lr;                 // 0..255
        offA[i] = (unsigned)((ra * 4 + (q ^ ((ra >> 1) & 3))) * 16);
    }
#pragma unroll
    for (int j = 0; j < 4; ++j) {
        int rb = wn * 64 + j * 16 + lr;                  // 0..127
        offB[j] = (unsigned)(16384 + (rb * 4 + (q ^ ((rb >> 1) & 3))) * 16);
    }

    floatx4 acc[8][4];
#pragma unroll
    for (int i = 0; i < 8; ++i)
#pragma unroll
        for (int j = 0; j < 4; ++j)
            acc[i][j] = floatx4{0.f, 0.f, 0.f, 0.f};

    const int kiters = K >> 5;

    // prologue: stage kt=0 into buf0
#pragma unroll
    for (int e = 0; e < 6; ++e)
        GLDS16(srcS[e], ldsS[e]);

    for (int kt = 0; kt < kiters; ++kt) {
        __syncthreads();   // drains buf[kt&1] loads (issued one full MFMA phase ago)
        const int cur = (kt & 1) * 24576;
        if (kt + 1 < kiters) {
            const int koff = (kt + 1) * 32;
            const int nxt  = ((kt + 1) & 1) * 24576;
#pragma unroll
            for (int e = 0; e < 6; ++e)
                GLDS16(srcS[e] + koff, ldsS[e] + nxt);
        }
        bf16x8 bv[4];
#pragma unroll
        for (int j = 0; j < 4; ++j) bv[j] = *(const bf16x8*)(smem + cur + offB[j]);
#pragma unroll
        for (int i = 0; i < 8; ++i) {
            bf16x8 av = *(const bf16x8*)(smem + cur + offA[i]);
#pragma unroll
            for (int j = 0; j < 4; ++j)
                acc[i][j] = __builtin_amdgcn_mfma_f32_16x16x32_bf16(av, bv[j], acc[i][j], 0, 0, 0);
        }
    }

    // ---- epilogue: per-wave LDS transpose of 16x64 slabs, then cell update.
    // Barriers fence write-phase vs read-phase (compiler memory ordering —
    // scalar float stores vs float4 loads are not TBAA-ordered without them).
    const int jg = j0 + wn * 16 + lr;
    float* scratch = (float*)(void*)smem + w * 1024;     // 4 KB per wave, wave-private

#pragma unroll
    for (int i = 0; i < 8; ++i) {
        __syncthreads();
#pragma unroll
        for (int j = 0; j < 4; ++j)
#pragma unroll
            for (int r = 0; r < 4; ++r)
                scratch[(q * 4 + r) * 64 + j * 16 + lr] = acc[i][j][r];  // C/D: row=q*4+r, col=lr
        __syncthreads();
#pragma unroll
        for (int p = 0; p < 4; ++p) {
            int row = q + p * 4;
            const float4 g = *(const float4*)(scratch + row * 64 + lr * 4);  // (i,f,g,o)
            int b = m0 + wm * 128 + i * 16 + row;
            const float4 gi = *(const float4*)(ginit + (size_t)b * gstride + (size_t)jg * 4);
            float iv = sigmf(g.x + gi.x);
            float fv = sigmf(g.y + gi.y);
            float gv = tanh_fast(g.z + gi.z);
            float ov = sigmf(g.w + gi.w);
            size_t ci = (size_t)b * HID + jg;
            float cn = fv * cell[ci] + iv * gv;
            cell[ci] = cn;
            float hv = ov * tanh_fast(cn);
            unsigned short hb = f2bf(hv);
            d1[(size_t)b * ld1 + off1 + jg] = hb;
            if (d2)  d2[(size_t)b * ld2 + off2 + jg] = hb;
            if (dfp) dfp[(size_t)b * HID + jg] = hv;
        }
    }
}

// ---- S0 = static @ W_ih0[:, :128]^T + b0, fp32, gate-interleaved output [b][j*4+gate]
// WT4 layout: wt4[k*4096 + j*4 + gate] = W_ih0[gate*1024+j][k], k<128
__global__ __launch_bounds__(256) void s0_gemm_tiled(
    const float* __restrict__ stat, const float* __restrict__ wt4,
    const float* __restrict__ bias4, float* __restrict__ s0)
{
    __shared__ float xl[32 * 128];   // 16 KB: 32 batch rows of static input
    const int tid = threadIdx.x;
    const int j0 = blockIdx.x * 64;
    const int b0 = blockIdx.y * 32;
#pragma unroll
    for (int r = 0; r < 4; ++r) {
        int f4 = r * 256 + tid;
        *(float4*)(xl + f4 * 4) = *(const float4*)(stat + (size_t)b0 * 128 + f4 * 4);
    }
    __syncthreads();
    const int j  = j0 + (tid & 63);
    const int wv = tid >> 6;
    float4 acc[8];
#pragma unroll
    for (int bb = 0; bb < 8; ++bb) acc[bb] = float4{0.f, 0.f, 0.f, 0.f};
#pragma unroll 4
    for (int k = 0; k < 128; ++k) {
        float4 w4 = *(const float4*)(wt4 + (size_t)k * 4096 + j * 4);
#pragma unroll
        for (int bb = 0; bb < 8; ++bb) {
            float xv = xl[(wv * 8 + bb) * 128 + k];
            acc[bb].x += xv * w4.x; acc[bb].y += xv * w4.y;
            acc[bb].z += xv * w4.z; acc[bb].w += xv * w4.w;
        }
    }
    float4 bi = *(const float4*)(bias4 + (size_t)j * 4);
#pragma unroll
    for (int bb = 0; bb < 8; ++bb) {
        int b = b0 + wv * 8 + bb;
        float4 o;
        o.x = acc[bb].x + bi.x; o.y = acc[bb].y + bi.y;
        o.z = acc[bb].z + bi.z; o.w = acc[bb].w + bi.w;
        *(float4*)(s0 + (size_t)b * 4096 + j * 4) = o;
    }
}

// y = h2_f32 @ Wout^T + bout (fp32); WoutT layout wt[k*64+o]; h2 staged in LDS.
__global__ __launch_bounds__(256) void out_gemm(
    const float* __restrict__ h2, const float* __restrict__ wt,
    const float* __restrict__ bout, float* __restrict__ y,
    unsigned short* __restrict__ xn)
{
    __shared__ float hl[8 * 1024];   // 32 KB: 8 h2 rows
    const int tid = threadIdx.x;
    const int b0 = blockIdx.x * 8;
#pragma unroll
    for (int r = 0; r < 8; ++r) {
        int f4 = r * 256 + tid;
        *(float4*)(hl + f4 * 4) = *(const float4*)(h2 + (size_t)b0 * 1024 + f4 * 4);
    }
    __syncthreads();
    const int o  = tid & 63;
    const int wv = tid >> 6;
    float acc0 = 0.f, acc1 = 0.f;
#pragma unroll 8
    for (int k = 0; k < 1024; ++k) {
        float wvv = wt[k * 64 + o];
        acc0 += hl[(wv * 2 + 0) * 1024 + k] * wvv;
        acc1 += hl[(wv * 2 + 1) * 1024 + k] * wvv;
    }
    float bo = bout[o];
    int b = b0 + wv * 2;
    float y0 = acc0 + bo, y1 = acc1 + bo;
    y[(size_t)b * LDY + o] = y0;
    y[(size_t)(b + 1) * LDY + o] = y1;
    xn[(size_t)b * KA + o] = f2bf(y0);
    xn[(size_t)(b + 1) * KA + o] = f2bf(y1);
}

// WT4[k*4096 + j*4 + gate] = W_ih0[(gate*1024+j)*192 + k]  (k < 128)
__global__ void build_wt0(const float* __restrict__ wih, float* __restrict__ wt4)
{
    int idx = blockIdx.x * 256 + threadIdx.x;   // 524288
    int gate = idx & 3, j = (idx >> 2) & 1023, k = idx >> 12;
    wt4[idx] = wih[(size_t)(gate * 1024 + j) * 192 + k];
}

// WoutT[k*64+o] = Wout[o*1024+k]
__global__ void build_woutT(const float* __restrict__ wout, float* __restrict__ wt)
{
    int idx = blockIdx.x * 256 + threadIdx.x;   // 65536
    int o = idx & 63, k = idx >> 6;
    wt[idx] = wout[(size_t)o * 1024 + k];
}

// interleaved bias: out[j*4+gate] = a[gate*1024+j] + b[gate*1024+j]
__global__ void build_bias(const float* __restrict__ a, const float* __restrict__ b,
                           float* __restrict__ o)
{
    int idx = blockIdx.x * 256 + threadIdx.x;   // 4096
    int gate = idx & 3, j = idx >> 2;
    int n = gate * 1024 + j;
    o[idx] = a[n] + b[n];
}

// W0[n][0:64] = W_ih0[n][128:192] (y-feedback cols), W0[n][64:1088] = W_hh0[n][:]
__global__ __launch_bounds__(256) void build_w0(
    const float* __restrict__ wih, const float* __restrict__ whh,
    unsigned short* __restrict__ w0)
{
    int idx = blockIdx.x * 256 + threadIdx.x;   // 4096*272 exact
    int n = idx / 272;
    int c = (idx - n * 272) * 4;
    float4 v;
    if (c < 64) v = *(const float4*)(wih + (size_t)n * 192 + 128 + c);
    else        v = *(const float4*)(whh + (size_t)n * 1024 + (c - 64));
    ushort4 o;
    o.x = f2bf(v.x); o.y = f2bf(v.y); o.z = f2bf(v.z); o.w = f2bf(v.w);
    *(ushort4*)(w0 + (size_t)n * KA + c) = o;
}

// W1[n][0:1024] = W_ih1[n][:], W1[n][1024:2048] = W_hh1[n][:]
__global__ __launch_bounds__(256) void build_w1(
    const float* __restrict__ wih, const float* __restrict__ whh,
    unsigned short* __restrict__ w1)
{
    int idx = blockIdx.x * 256 + threadIdx.x;   // 4096*512 exact
    int n = idx >> 9;
    int c = (idx & 511) * 4;
    float4 v;
    if (c < 1024) v = *(const float4*)(wih + (size_t)n * 1024 + c);
    else          v = *(const float4*)(whh + (size_t)n * 1024 + (c - 1024));
    ushort4 o;
    o.x = f2bf(v.x); o.y = f2bf(v.y); o.z = f2bf(v.z); o.w = f2bf(v.w);
    *(ushort4*)(w1 + (size_t)n * KB + c) = o;
}

extern "C" void kernel_launch(void* const* d_in, const int* in_sizes, int n_in,
                              void* d_out, int out_size, void* d_ws, size_t ws_size,
                              hipStream_t stream)
{
    (void)in_sizes; (void)n_in; (void)out_size; (void)ws_size;
    const float* static_in = (const float*)d_in[0];
    const float* Wih0 = (const float*)d_in[1];
    const float* Whh0 = (const float*)d_in[2];
    const float* bih0 = (const float*)d_in[3];
    const float* bhh0 = (const float*)d_in[4];
    const float* Wih1 = (const float*)d_in[5];
    const float* Whh1 = (const float*)d_in[6];
    const float* bih1 = (const float*)d_in[7];
    const float* bhh1 = (const float*)d_in[8];
    const float* Wout = (const float*)d_in[9];
    const float* bout = (const float*)d_in[10];
    float* out = (float*)d_out;

    char* p = (char*)d_ws;
    size_t off = 0;
    auto take = [&](size_t n) { char* r = p + off; off += (n + 255) & ~(size_t)255; return r; };

    unsigned short* W0   = (unsigned short*)take((size_t)4096 * KA * 2);
    unsigned short* W1   = (unsigned short*)take((size_t)4096 * KB * 2);
    float*          B1b  = (float*)take(4096 * 4);
    float*          B0b  = (float*)take(4096 * 4);
    float*          WT0  = (float*)take((size_t)128 * 4096 * 4);
    float*          WoT  = (float*)take((size_t)1024 * 64 * 4);
    float*          S0   = (float*)take((size_t)BATCH * 4096 * 4);
    float*          H2f  = (float*)take((size_t)BATCH * HID * 4);
    float*          C1   = (float*)take((size_t)BATCH * HID * 4);
    float*          C2   = (float*)take((size_t)BATCH * HID * 4);
    unsigned short* X0a  = (unsigned short*)take((size_t)BATCH * KA * 2);
    unsigned short* X0b  = (unsigned short*)take((size_t)BATCH * KA * 2);
    unsigned short* X1a  = (unsigned short*)take((size_t)BATCH * KB * 2);
    unsigned short* X1b  = (unsigned short*)take((size_t)BATCH * KB * 2);
    // total ~190 MiB

    hipMemsetAsync(C1, 0, (size_t)BATCH * HID * 4, stream);
    hipMemsetAsync(C2, 0, (size_t)BATCH * HID * 4, stream);
    hipMemsetAsync(X0a, 0, (size_t)BATCH * KA * 2, stream);   // y0 = h1_0 = 0
    hipMemsetAsync(X1a, 0, (size_t)BATCH * KB * 2, stream);   // h2_0 = 0

    build_w0<<<4352, 256, 0, stream>>>(Wih0, Whh0, W0);
    build_w1<<<8192, 256, 0, stream>>>(Wih1, Whh1, W1);
    build_wt0<<<2048, 256, 0, stream>>>(Wih0, WT0);
    build_woutT<<<256, 256, 0, stream>>>(Wout, WoT);
    build_bias<<<16, 256, 0, stream>>>(bih0, bhh0, B0b);
    build_bias<<<16, 256, 0, stream>>>(bih1, bhh1, B1b);
    s0_gemm_tiled<<<dim3(16, 128), 256, 0, stream>>>(static_in, WT0, B0b, S0);

    dim3 grid(16, 32);   // 512 blocks = 2 per CU exact
    for (int t = 0; t < TSTEPS; ++t) {
        unsigned short* X0c = (t & 1) ? X0b : X0a;
        unsigned short* X0n = (t & 1) ? X0a : X0b;
        unsigned short* X1c = (t & 1) ? X1b : X1a;
        unsigned short* X1n = (t & 1) ? X1a : X1b;
        // layer 0: gates = X0c @ W0^T + S0[b]; h1 -> X1c[:,0:1024] and X0n[:,64:1088]
        lstm_gate_gemm<<<grid, 256, 0, stream>>>(X0c, KA, W0, S0, 4096, C1,
                                                 X1c, KB, 0, X0n, KA, 64, nullptr);
        // layer 1: gates = X1c @ W1^T + b1 (interleaved); h2 -> X1n[:,1024:2048] + H2f
        lstm_gate_gemm<<<grid, 256, 0, stream>>>(X1c, KB, W1, B1b, 0, C2,
                                                 X1n, KB, 1024, nullptr, 0, 0, H2f);
        // y_t = H2f @ WoutT + bout -> out[:,t,:] and X0n[:,0:64]
        out_gemm<<<512, 256, 0, stream>>>(H2f, WoT, bout, out + t * NOUT, X0n);
    }
}